// Round 12
// baseline (707.536 us; speedup 1.0000x reference)
//
#include <hip/hip_runtime.h>
#include <hip/hip_bf16.h>
#include <cstdint>
#include <cstddef>

#define BB    2
#define TSEQ  512
#define EDIM  768
#define NHEAD 12
#define HDIM  64
#define VDIM  256
#define PDIM  4
#define NROW  (BB*TSEQ)        // 1024
#define NROW2 (BB*TSEQ*PDIM)   // 4096

typedef __attribute__((ext_vector_type(8))) short short8;
typedef __attribute__((ext_vector_type(4))) short short4v;
typedef __attribute__((ext_vector_type(4))) float floatx4;

__device__ __forceinline__ float gelu_f(float v){
    return 0.5f * v * (1.0f + erff(v * 0.70710678118654752f));
}
__device__ __forceinline__ float b2f(short s){
    unsigned u = ((unsigned)(unsigned short)s) << 16;
    float f; __builtin_memcpy(&f, &u, 4); return f;
}
__device__ __forceinline__ short f2bs(float v){
    __hip_bfloat16 h = __float2bfloat16(v);
    short s; __builtin_memcpy(&s, &h, 2); return s;
}
__device__ __forceinline__ void gload16(const void* g, void* l){
    __builtin_amdgcn_global_load_lds((const __attribute__((address_space(1))) void*)g,
                                     (__attribute__((address_space(3))) void*)l, 16, 0, 0);
}

// emit s_waitcnt vmcnt(<literal n>)
#define WAITN(n) asm volatile("s_waitcnt vmcnt(" #n ")" ::: "memory")
// 4-stage pipeline wait: steady keeps 2 future stages in flight.
#define WAIT_STAGE(rem, full, half)                         \
    do{ if((rem) >= 2)      WAITN(full);                    \
        else if((rem) == 1) WAITN(half);                    \
        else                WAITN(0);                       \
        asm volatile("s_barrier" ::: "memory"); }while(0)
// 8-stage pipeline wait, 2 loads/issue: steady keeps 6 stages (12 loads).
#define WAIT_STAGE8T(rem)                                   \
    do{ if((rem) >= 6)      WAITN(12);                      \
        else if((rem) == 5) WAITN(10);                      \
        else if((rem) == 4) WAITN(8);                       \
        else if((rem) == 3) WAITN(6);                       \
        else if((rem) == 2) WAITN(4);                       \
        else if((rem) == 1) WAITN(2);                       \
        else                WAITN(0);                       \
        asm volatile("s_barrier" ::: "memory"); }while(0)

// ---------------------------------------------------------------------------
// All 17 weight conversions in one dispatch. fp32 [K,N] -> bf16 [N,K].
// 128x128 tiles; 8-deep load batches; bf16 LDS with XOR swizzle.
// ---------------------------------------------------------------------------
struct WD2 { const float* in; __hip_bfloat16* out; int K; int N; int nt; };
struct WDs { WD2 d[17]; };

__global__ __launch_bounds__(256) void wconv_all(WDs a)
{
    int id = blockIdx.x;
    int i = 0;
    while(i < 16 && id >= a.d[i].nt){ id -= a.d[i].nt; i++; }
    WD2 w = a.d[i];
    const int tx = w.N / 128;
    const int n0 = (id % tx) * 128, k0 = (id / tx) * 128;
    __shared__ short t[128*128];           // 32 KB, bf16, swizzled
    {
        const int c4 = (threadIdx.x & 31) * 4;   // n within tile
        const int r0 = threadIdx.x >> 5;         // 0..7
        #pragma unroll
        for(int half = 0; half < 2; half++){
            float4 v[8];
            #pragma unroll
            for(int it = 0; it < 8; it++){
                int r = r0 + it*8 + half*64;
                v[it] = *(const float4*)(w.in + (size_t)(k0 + r) * w.N + n0 + c4);
            }
            #pragma unroll
            for(int it = 0; it < 8; it++){
                int r = r0 + it*8 + half*64;
                int nswz = c4 ^ (((r >> 3) & 15) << 2);
                short4v o;
                o[0] = f2bs(v[it].x); o[1] = f2bs(v[it].y);
                o[2] = f2bs(v[it].z); o[3] = f2bs(v[it].w);
                *(short4v*)&t[r*128 + nswz] = o;
            }
        }
    }
    __syncthreads();
    {
        const int k8 = (threadIdx.x & 15) * 8;     // 0..120
        const int nr = threadIdx.x >> 4;           // 0..15
        const int swz = (k8 >> 3) << 2;
        #pragma unroll
        for(int pass = 0; pass < 8; pass++){
            int n = nr + pass*16;
            int nswz = n ^ swz;
            short8 o;
            #pragma unroll
            for(int j = 0; j < 8; j++) o[j] = t[(k8 + j)*128 + nswz];
            *(short8*)((short*)w.out + (size_t)(n0 + n) * w.K + k0 + k8) = o;
        }
    }
}

// ---------------------------------------------------------------------------
// MFMA GEMM 64x64 "q" variant: 4 waves, each owning 16 rows x ALL 64 cols
// (acc[4] along N). 32 KB LDS -> 5 blocks/CU; 4-stage counted-vmcnt.
// EPI: 1 = bias+gelu bf16; 2 = layer-qkv RoPE head-major; 3 = SA RoPE (p=row%4).
// ---------------------------------------------------------------------------
template<int EPI>
__global__ __launch_bounds__(256) void gemm64q(
    const short* __restrict__ A, const short* __restrict__ Bt,
    const float* __restrict__ bias, __hip_bfloat16* __restrict__ Cout,
    __hip_bfloat16* __restrict__ qrb, __hip_bfloat16* __restrict__ krb,
    __hip_bfloat16* __restrict__ vvb,
    const float* __restrict__ rc, const float* __restrict__ rs,
    int M, int N, int K)
{
    alignas(16) __shared__ short As[4*64*32];    // 16 KB
    alignas(16) __shared__ short Bs[4*64*32];    // 16 KB
    const int tid  = threadIdx.x;
    const int lane = tid & 63;
    const int wave = tid >> 6;
    const int bm = blockIdx.y * 64, bn = blockIdx.x * 64;
    const int wm = wave * 16;                    // 16 rows per wave
    const int quad = lane >> 4, l16 = lane & 15;

    floatx4 acc[4];
    #pragma unroll
    for(int j = 0; j < 4; j++) acc[j] = floatx4{0.f, 0.f, 0.f, 0.f};

    const int r  = tid >> 2;
    const int c8 = (tid & 3) * 8;
    const int ldsoff = (tid & 192) * 16;

    auto issue = [&](int k0, int cur){
        char* ab = (char*)As + cur*4096 + ldsoff;
        char* bb = (char*)Bs + cur*4096 + ldsoff;
        gload16(A  + (size_t)(bm + r) * K + k0 + c8, ab);
        gload16(Bt + (size_t)(bn + r) * K + k0 + c8, bb);
    };

    const int niter = K >> 5;                 // >= 8 at all call sites
    issue(0, 0); issue(32, 1); issue(64, 2);
    for(int it = 0; it < niter; it++){
        WAIT_STAGE(niter - 1 - it, 4, 2);     // 2 loads/issue
        if(it + 3 < niter) issue((it + 3) << 5, (it + 3) & 3);
        const short* Ab = As + (it & 3) * 2048;
        const short* Bb = Bs + (it & 3) * 2048;
        short8 af = *(const short8*)&Ab[(wm + l16)*32 + quad*8];
        short8 bfr[4];
        #pragma unroll
        for(int j = 0; j < 4; j++)
            bfr[j] = *(const short8*)&Bb[(j*16 + l16)*32 + quad*8];
        #pragma unroll
        for(int j = 0; j < 4; j++)
            acc[j] = __builtin_amdgcn_mfma_f32_16x16x32_bf16(af, bfr[j], acc[j], 0, 0, 0);
    }

    if(EPI == 2){
        // layer qkv: RoPE + head-major stores. Wave holds all 64 cols (one head).
        const int region = bn / 768;       // 0=q, 1=k, 2=v
        const int h = (bn % 768) >> 6;
        #pragma unroll
        for(int rr = 0; rr < 4; rr++){
            int row = bm + wm + quad*4 + rr;
            int t = row & (TSEQ-1), b = row >> 9;
            float a0 = acc[0][rr], a1 = acc[1][rr];
            float a2 = acc[2][rr], a3 = acc[3][rr];
            size_t dbase = ((size_t)(b*NHEAD + h)*TSEQ + t)*HDIM;
            if(region == 2){
                vvb[dbase + l16]      = __float2bfloat16(a0);
                vvb[dbase + 16 + l16] = __float2bfloat16(a1);
                vvb[dbase + 32 + l16] = __float2bfloat16(a2);
                vvb[dbase + 48 + l16] = __float2bfloat16(a3);
            }else{
                float c0 = rc[t*32 + l16],      s0 = rs[t*32 + l16];
                float c1 = rc[t*32 + 16 + l16], s1 = rs[t*32 + 16 + l16];
                __hip_bfloat16* dst = (region == 0) ? qrb : krb;
                dst[dbase + l16]      = __float2bfloat16(a0*c0 - a2*s0);
                dst[dbase + 16 + l16] = __float2bfloat16(a1*c1 - a3*s1);
                dst[dbase + 32 + l16] = __float2bfloat16(a0*s0 + a2*c0);
                dst[dbase + 48 + l16] = __float2bfloat16(a1*s1 + a3*c1);
            }
        }
        return;
    }

    if(EPI == 3){
        // SA qkv: RoPE at p = row%4, row-major bf16 store.
        const int region = bn / 768;
        #pragma unroll
        for(int rr = 0; rr < 4; rr++){
            int row = bm + wm + quad*4 + rr;
            float a0 = acc[0][rr], a1 = acc[1][rr];
            float a2 = acc[2][rr], a3 = acc[3][rr];
            size_t rowb = (size_t)row * N + bn;
            if(region == 2){
                Cout[rowb + l16]      = __float2bfloat16(a0);
                Cout[rowb + 16 + l16] = __float2bfloat16(a1);
                Cout[rowb + 32 + l16] = __float2bfloat16(a2);
                Cout[rowb + 48 + l16] = __float2bfloat16(a3);
            }else{
                int p = row & 3;
                float c0 = rc[p*32 + l16],      s0 = rs[p*32 + l16];
                float c1 = rc[p*32 + 16 + l16], s1 = rs[p*32 + 16 + l16];
                Cout[rowb + l16]      = __float2bfloat16(a0*c0 - a2*s0);
                Cout[rowb + 16 + l16] = __float2bfloat16(a1*c1 - a3*s1);
                Cout[rowb + 32 + l16] = __float2bfloat16(a0*s0 + a2*c0);
                Cout[rowb + 48 + l16] = __float2bfloat16(a1*s1 + a3*c1);
            }
        }
        return;
    }

    // EPI == 1: bias + gelu, bf16 store
    #pragma unroll
    for(int j = 0; j < 4; j++){
        int col = bn + j*16 + l16;
        float bv = bias ? bias[col] : 0.f;
        #pragma unroll
        for(int rr = 0; rr < 4; rr++){
            int row = bm + wm + quad*4 + rr;
            float v = acc[j][rr] + bv;
            v = gelu_f(v);
            Cout[(size_t)row * N + col] = __float2bfloat16(v);
        }
    }
}

// ---------------------------------------------------------------------------
// 64x64-tile GEMM (bf16 A), 8-stage counted-vmcnt pipeline (6 stages ~900 cy
// in flight). 64 KB LDS -> 2 blocks/CU cap; all call sites run <= 1 block/CU
// so no occupancy cost. fp32 out, optional resid add, fused p==0 slice (OUTC).
// ---------------------------------------------------------------------------
template<int RESID, int OUTC>
__global__ __launch_bounds__(256) void gemm64t(
    const short* __restrict__ A, const short* __restrict__ Bt,
    const float* __restrict__ bias, const float* __restrict__ resid,
    float* __restrict__ Cf, float* __restrict__ outp, int M, int N, int K)
{
    alignas(16) __shared__ short As[8*64*32];    // 32 KB
    alignas(16) __shared__ short Bs[8*64*32];    // 32 KB
    const int tid  = threadIdx.x;
    const int lane = tid & 63;
    const int wave = tid >> 6;
    const int bm = blockIdx.y * 64, bn = blockIdx.x * 64;
    const int wm = (wave >> 1) * 32, wn = (wave & 1) * 32;
    const int quad = lane >> 4, l16 = lane & 15;

    floatx4 acc[2][2];
    #pragma unroll
    for(int i = 0; i < 2; i++)
        #pragma unroll
        for(int j = 0; j < 2; j++)
            acc[i][j] = floatx4{0.f, 0.f, 0.f, 0.f};

    const int r  = tid >> 2;
    const int c8 = (tid & 3) * 8;
    const int ldsoff = (tid & 192) * 16;

    auto issue = [&](int k0, int cur){
        char* ab = (char*)As + cur*4096 + ldsoff;
        char* bb = (char*)Bs + cur*4096 + ldsoff;
        gload16(A  + (size_t)(bm + r) * K + k0 + c8, ab);
        gload16(Bt + (size_t)(bn + r) * K + k0 + c8, bb);
    };

    const int niter = K >> 5;                 // >= 24 at all call sites
    issue(0, 0); issue(32, 1); issue(64, 2); issue(96, 3);
    issue(128, 4); issue(160, 5); issue(192, 6);
    for(int it = 0; it < niter; it++){
        WAIT_STAGE8T(niter - 1 - it);         // 2 loads/issue
        if(it + 7 < niter) issue((it + 7) << 5, (it + 7) & 7);
        const short* Ab = As + (it & 7) * 2048;
        const short* Bb = Bs + (it & 7) * 2048;
        short8 af[2], bfr[2];
        #pragma unroll
        for(int i = 0; i < 2; i++){
            af[i]  = *(const short8*)&Ab[(wm + i*16 + l16)*32 + quad*8];
            bfr[i] = *(const short8*)&Bb[(wn + i*16 + l16)*32 + quad*8];
        }
        #pragma unroll
        for(int i = 0; i < 2; i++)
            #pragma unroll
            for(int j = 0; j < 2; j++)
                acc[i][j] = __builtin_amdgcn_mfma_f32_16x16x32_bf16(af[i], bfr[j], acc[i][j], 0, 0, 0);
    }

    #pragma unroll
    for(int i = 0; i < 2; i++){
        int row0 = bm + wm + i*16 + quad*4;
        #pragma unroll
        for(int j = 0; j < 2; j++){
            int col = bn + wn + j*16 + l16;
            float bv = bias ? bias[col] : 0.f;
            #pragma unroll
            for(int rr = 0; rr < 4; rr++){
                int row = row0 + rr;
                float v = acc[i][j][rr] + bv;
                if(RESID) v += resid[(size_t)row * N + col];
                Cf[(size_t)row * N + col] = v;
                if(OUTC && (row & 3) == 0)
                    outp[(size_t)(row >> 2) * N + col] = v;
            }
        }
    }
}

// ---------------------------------------------------------------------------
// LayerNorm, wave-per-row (4 rows/block). fp32 in (optionally +in2), bf16 out.
// ---------------------------------------------------------------------------
template<int D>
__global__ __launch_bounds__(256) void ln_wave(
    const float* __restrict__ in, const float* __restrict__ in2,
    const float* __restrict__ g, const float* __restrict__ bta,
    __hip_bfloat16* __restrict__ out)
{
    constexpr int NC = D / 256;                 // float4 chunks per lane
    const int row  = blockIdx.x * 4 + (threadIdx.x >> 6);
    const int lane = threadIdx.x & 63;
    const float* xr = in + (size_t)row * D;
    float4 v[NC];
    float sum = 0.f, sq = 0.f;
    #pragma unroll
    for(int j = 0; j < NC; j++){
        int d0 = (lane + 64*j) * 4;
        v[j] = *(const float4*)(xr + d0);
        if(in2){
            float4 u = *(const float4*)(in2 + (size_t)row * D + d0);
            v[j].x += u.x; v[j].y += u.y; v[j].z += u.z; v[j].w += u.w;
        }
        sum += v[j].x + v[j].y + v[j].z + v[j].w;
        sq  += v[j].x*v[j].x + v[j].y*v[j].y + v[j].z*v[j].z + v[j].w*v[j].w;
    }
    #pragma unroll
    for(int off = 32; off > 0; off >>= 1){
        sum += __shfl_xor(sum, off, 64);
        sq  += __shfl_xor(sq,  off, 64);
    }
    const float m    = sum / D;
    const float rstd = rsqrtf(fmaxf(sq / D - m*m, 0.f) + 1e-5f);
    #pragma unroll
    for(int j = 0; j < NC; j++){
        int d0 = (lane + 64*j) * 4;
        float4 gg = *(const float4*)(g + d0);
        float4 bb = *(const float4*)(bta + d0);
        short4v o;
        o[0] = f2bs((v[j].x - m) * rstd * gg.x + bb.x);
        o[1] = f2bs((v[j].y - m) * rstd * gg.y + bb.y);
        o[2] = f2bs((v[j].z - m) * rstd * gg.z + bb.z);
        o[3] = f2bs((v[j].w - m) * rstd * gg.w + bb.w);
        *(short4v*)((short*)out + (size_t)row * D + d0) = o;
    }
}

// ---------------------------------------------------------------------------
// Fused embed (blocks 0..NROW-1) + rope table build (blocks NROW..NROW+63).
// ---------------------------------------------------------------------------
__global__ __launch_bounds__(256) void embed_rope(
    const int* __restrict__ tokens, const float* __restrict__ emb,
    float* __restrict__ x0, float* __restrict__ x,
    float* __restrict__ rc, float* __restrict__ rs)
{
    const int blk = blockIdx.x;
    if(blk < NROW){
        const int tok = tokens[blk];
        const float4* src = (const float4*)(emb + (size_t)tok * EDIM);
        float4* d0 = (float4*)(x0 + (size_t)blk * EDIM);
        float4* d1 = (float4*)(x  + (size_t)blk * EDIM);
        if(threadIdx.x < EDIM/4){
            float4 v = src[threadIdx.x]; d0[threadIdx.x] = v; d1[threadIdx.x] = v;
        }
        return;
    }
    int i = (blk - NROW) * 256 + threadIdx.x;   // 64*256 = 16384
    int pos = i >> 5, d = i & 31;
    float inv = powf(10000.0f, -(float)(2*d) / 64.0f);
    float f = (float)pos * inv;
    rc[i] = cosf(f);
    rs[i] = sinf(f);
}

// ---------------------------------------------------------------------------
// Sliding-window attention. 16 queries/block (4 waves x 4 queries each),
// shared S+15-row K/V window.
// ---------------------------------------------------------------------------
template<int S>
__global__ __launch_bounds__(256) void patch_attn16(
    const __hip_bfloat16* __restrict__ qr, const __hip_bfloat16* __restrict__ kr,
    const __hip_bfloat16* __restrict__ vv, float* __restrict__ x)
{
    constexpr int W = S + 15;
    alignas(16) __shared__ short Ks[W*64];
    alignas(16) __shared__ short Vs[W*64];
    __shared__ float qlds[16*64];
    __shared__ float pb[16*128];

    const int t0 = blockIdx.x * 16;
    const int h = blockIdx.y, b = blockIdx.z;
    const int tid = threadIdx.x;
    const int wv = tid >> 6, lane = tid & 63;
    const size_t headbase = ((size_t)(b*NHEAD + h)) * TSEQ;

    const int c = tid & 7;
    for(int r = tid >> 3; r < W; r += 32){
        int g = t0 - S + 1 + r;
        int gc = g < 0 ? 0 : g;
        int sc = (c ^ (r & 7)) * 8;
        *(short8*)&Ks[r*64 + sc] = *(const short8*)((const short*)kr + (headbase + gc)*64 + c*8);
        *(short8*)&Vs[r*64 + sc] = *(const short8*)((const short*)vv + (headbase + gc)*64 + c*8);
    }
    for(int i = tid; i < 16*64; i += 256)
        qlds[i] = __bfloat162float(qr[(headbase + t0 + (i >> 6))*64 + (i & 63)]);
    __syncthreads();

    #pragma unroll
    for(int qq = 0; qq < 4; qq++){
        const int ql = wv*4 + qq;          // local query index 0..15
        const int t  = t0 + ql;
        const int r0 = (S >= 64) ? (ql + lane) : ((lane < S) ? (ql + lane) : 0);
        const int r1 = ql + lane + 64;
        float a0 = 0.f, a1 = 0.f;
        #pragma unroll
        for(int ch = 0; ch < 8; ch++){
            float4 qa = *(const float4*)&qlds[ql*64 + ch*8];
            float4 qb = *(const float4*)&qlds[ql*64 + ch*8 + 4];
            short8 k0 = *(const short8*)&Ks[r0*64 + ((ch ^ (r0 & 7))*8)];
            a0 += qa.x*b2f(k0[0]) + qa.y*b2f(k0[1]) + qa.z*b2f(k0[2]) + qa.w*b2f(k0[3])
                + qb.x*b2f(k0[4]) + qb.y*b2f(k0[5]) + qb.z*b2f(k0[6]) + qb.w*b2f(k0[7]);
            if(S == 128){
                short8 k1 = *(const short8*)&Ks[r1*64 + ((ch ^ (r1 & 7))*8)];
                a1 += qa.x*b2f(k1[0]) + qa.y*b2f(k1[1]) + qa.z*b2f(k1[2]) + qa.w*b2f(k1[3])
                    + qb.x*b2f(k1[4]) + qb.y*b2f(k1[5]) + qb.z*b2f(k1[6]) + qb.w*b2f(k1[7]);
            }
        }
        const int key0 = t - S + 1 + lane;
        const bool v0 = (lane < S) && (key0 >= 0);
        const bool v1 = (S == 128) && (key0 + 64 >= 0);
        float s0 = v0 ? a0 * 0.125f : -1e30f;
        float s1 = v1 ? a1 * 0.125f : -1e30f;
        float mx = fmaxf(s0, s1);
        #pragma unroll
        for(int off = 32; off > 0; off >>= 1) mx = fmaxf(mx, __shfl_xor(mx, off, 64));
        float p0 = v0 ? expf(s0 - mx) : 0.f;
        float p1 = v1 ? expf(s1 - mx) : 0.f;
        float sm = p0 + p1;
        #pragma unroll
        for(int off = 32; off > 0; off >>= 1) sm += __shfl_xor(sm, off, 64);
        const float inv = 1.f / sm;
        pb[ql*128 + lane] = p0 * inv;
        if(S == 128) pb[ql*128 + lane + 64] = p1 * inv;
    }
    // pb rows are wave-local (each wave reads only its own ql rows) -> no barrier

    const int d = lane;
    const int coff = d >> 3, dlo = d & 7;
    #pragma unroll
    for(int qq = 0; qq < 4; qq++){
        const int ql = wv*4 + qq;
        float o = 0.f;
        #pragma unroll 8
        for(int j = 0; j < S; j++){
            int r = ql + j;
            float p = pb[ql*128 + j];
            o += p * b2f(Vs[r*64 + ((coff ^ (r & 7))*8) + dlo]);
        }
        x[((size_t)(b*TSEQ) + t0 + ql) * EDIM + h*HDIM + d] += o;
    }
}

// ---------------------------------------------------------------------------
// P-axis attention: q/k already rotated by saqkv epilogue.
// ---------------------------------------------------------------------------
__global__ __launch_bounds__(256) void sa_attn(
    const __hip_bfloat16* __restrict__ qkv2, __hip_bfloat16* __restrict__ o)
{
    const int t = blockIdx.x, h = blockIdx.y, b = blockIdx.z;
    const int p = threadIdx.x >> 6, lane = threadIdx.x & 63;
    const int row0 = (b*TSEQ + t) * PDIM;
    const short* base = (const short*)qkv2 + (size_t)row0 * (3*EDIM);
    const int d = lane;
    float q = b2f(base[(size_t)p*(3*EDIM) + h*HDIM + d]);
    float sc[4];
    #pragma unroll
    for(int j = 0; j < 4; j++){
        float kj = b2f(base[(size_t)j*(3*EDIM) + EDIM + h*HDIM + d]);
        float v = q * kj;
        #pragma unroll
        for(int off = 32; off > 0; off >>= 1) v += __shfl_xor(v, off, 64);
        sc[j] = v * 0.125f;
    }
    float m = fmaxf(fmaxf(sc[0], sc[1]), fmaxf(sc[2], sc[3]));
    float e0 = expf(sc[0]-m), e1 = expf(sc[1]-m), e2 = expf(sc[2]-m), e3 = expf(sc[3]-m);
    float idn = 1.f / (e0 + e1 + e2 + e3);
    float ov = (e0 * b2f(base[0*(3*EDIM) + 2*EDIM + h*HDIM + d])
              + e1 * b2f(base[1*(3*EDIM) + 2*EDIM + h*HDIM + d])
              + e2 * b2f(base[2*(3*EDIM) + 2*EDIM + h*HDIM + d])
              + e3 * b2f(base[3*(3*EDIM) + 2*EDIM + h*HDIM + d])) * idn;
    o[(size_t)(row0 + p) * EDIM + h*HDIM + d] = __float2bfloat16(ov);
}

// ---------------------------------------------------------------------------
extern "C" void kernel_launch(void* const* d_in, const int* in_sizes, int n_in,
                              void* d_out, int out_size, void* d_ws, size_t ws_size,
                              hipStream_t stream)
{
    const int*   tokens    = (const int*)  d_in[0];
    const float* emb       = (const float*)d_in[1];
    const float* bl0g      = (const float*)d_in[2];
    const float* bl0b      = (const float*)d_in[3];
    const float* bl1g      = (const float*)d_in[4];
    const float* bl1b      = (const float*)d_in[5];
    const float* qkv_w     = (const float*)d_in[6];
    const float* ff_w1     = (const float*)d_in[7];
    const float* ff_b1     = (const float*)d_in[8];
    const float* ff_w2     = (const float*)d_in[9];
    const float* ff_b2     = (const float*)d_in[10];
    const float* fin_g     = (const float*)d_in[11];
    const float* fin_b     = (const float*)d_in[12];
    const float* head_w    = (const float*)d_in[13];
    const float* head_b    = (const float*)d_in[14];
    const float* sa_ln0_g  = (const float*)d_in[15];
    const float* sa_ln0_b  = (const float*)d_in[16];
    const float* sa_ln1_g  = (const float*)d_in[17];
    const float* sa_ln1_b  = (const float*)d_in[18];
    const float* sa_qkv_w  = (const float*)d_in[19];
    const float* sa_proj_w = (const float*)d_in[20];
    const float* sa_proj_b = (const float*)d_in[21];
    const float* sa_ff_w1  = (const float*)d_in[22];
    const float* sa_ff_b1  = (const float*)d_in[23];
    const float* sa_ff_w2  = (const float*)d_in[24];
    const float* sa_ff_b2  = (const float*)d_in[25];
    float* out = (float*)d_out;

    // ---- workspace carve-up (~94 MB; harness provides 256 MiB) ----
    char* p = (char*)d_ws;
    auto alloc = [&](size_t bytes){ char* q = p; p += (bytes + 255) & ~(size_t)255; return q; };

    float* logits = (float*)alloc((size_t)NROW2*VDIM*4);        // 4 MB
    float* ropec  = (float*)alloc(512*32*4);
    float* ropes  = (float*)alloc(512*32*4);
    __hip_bfloat16* wqkvT[4]; for(int i=0;i<4;i++) wqkvT[i] = (__hip_bfloat16*)alloc((size_t)768*2304*2);
    __hip_bfloat16* wff1T[4]; for(int i=0;i<4;i++) wff1T[i] = (__hip_bfloat16*)alloc((size_t)768*3072*2);
    __hip_bfloat16* wff2T[4]; for(int i=0;i<4;i++) wff2T[i] = (__hip_bfloat16*)alloc((size_t)3072*768*2);
    __hip_bfloat16* wheadT   = (__hip_bfloat16*)alloc((size_t)768*1024*2);
    __hip_bfloat16* wsaqkvT  = (__hip_bfloat16*)alloc((size_t)256*2304*2);
    __hip_bfloat16* wsaprojT = (__hip_bfloat16*)alloc((size_t)768*256*2);
    __hip_bfloat16* wsaff1T  = (__hip_bfloat16*)alloc((size_t)256*1024*2);
    __hip_bfloat16* wsaff2T  = (__hip_bfloat16*)alloc((size_t)1024*256*2);
    char* U = p;
    // phase 1
    float* x0           = (float*)(U);                           // 3,145,728
    float* x            = (float*)(U + 3145728);                 // 3,145,728
    __hip_bfloat16* h   = (__hip_bfloat16*)(U + 6291456);        // 1,572,864
    __hip_bfloat16* ff1 = (__hip_bfloat16*)(U + 7864320);        // 6,291,456
    __hip_bfloat16* qrb = (__hip_bfloat16*)(U + 14155776);       // 1,572,864
    __hip_bfloat16* krb = (__hip_bfloat16*)(U + 15728640);       // 1,572,864
    __hip_bfloat16* vvb = (__hip_bfloat16*)(U + 17301504);       // 1,572,864
    // phase 2 (aliases phase 1 — dead after head GEMM)
    __hip_bfloat16* h2    = (__hip_bfloat16*)(U);                // 2,097,152
    __hip_bfloat16* qkv2  = (__hip_bfloat16*)(U + 2097152);      // 18,874,368
    __hip_bfloat16* sa_o  = (__hip_bfloat16*)(U + 20971520);     // 6,291,456
    __hip_bfloat16* sa_f1 = (__hip_bfloat16*)(U + 27262976);     // 8,388,608

    // ---- prologue: embed+rope fused + all 17 weight converts in ONE dispatch ----
    embed_rope<<<NROW + 64, 256, 0, stream>>>(tokens, emb, x0, x, ropec, ropes);
    {
        WDs wds; int tot = 0, n = 0;
        auto add = [&](const float* in, __hip_bfloat16* o2, int K, int N){
            wds.d[n++] = WD2{in, o2, K, N, (N/128)*(K/128)};
            tot += (N/128)*(K/128);
        };
        for(int i=0;i<4;i++){
            add(qkv_w + (size_t)i*768*2304, wqkvT[i], 768, 2304);
            add(ff_w1 + (size_t)i*768*3072, wff1T[i], 768, 3072);
            add(ff_w2 + (size_t)i*3072*768, wff2T[i], 3072, 768);
        }
        add(head_w,    wheadT,   768, 1024);
        add(sa_qkv_w,  wsaqkvT,  256, 2304);
        add(sa_proj_w, wsaprojT, 768, 256);
        add(sa_ff_w1,  wsaff1T,  256, 1024);
        add(sa_ff_w2,  wsaff2T, 1024, 256);
        wconv_all<<<tot, 256, 0, stream>>>(wds);
    }

    // ---- 4 main layers ----
    for(int i = 0; i < 4; i++){
        ln_wave<EDIM><<<NROW/4, 256, 0, stream>>>(x, nullptr, bl0g + i*EDIM, bl0b + i*EDIM, h);
        gemm64q<2><<<dim3(36, 16), 256, 0, stream>>>(
            (const short*)h, (const short*)wqkvT[i], nullptr, nullptr,
            qrb, krb, vvb, ropec, ropes, NROW, 3*EDIM, EDIM);
        dim3 agrid(TSEQ/16, NHEAD, BB);
        if(i == 0)      patch_attn16<16><<<agrid, 256, 0, stream>>>(qrb, krb, vvb, x);
        else if(i == 1) patch_attn16<32><<<agrid, 256, 0, stream>>>(qrb, krb, vvb, x);
        else if(i == 2) patch_attn16<64><<<agrid, 256, 0, stream>>>(qrb, krb, vvb, x);
        else            patch_attn16<128><<<agrid, 256, 0, stream>>>(qrb, krb, vvb, x);
        ln_wave<EDIM><<<NROW/4, 256, 0, stream>>>(x, nullptr, bl1g + i*EDIM, bl1b + i*EDIM, h);
        gemm64q<1><<<dim3(48, 16), 256, 0, stream>>>(
            (const short*)h, (const short*)wff1T[i], ff_b1 + (size_t)i*4*EDIM, ff1,
            nullptr, nullptr, nullptr, nullptr, nullptr, NROW, 4*EDIM, EDIM);
        gemm64t<1,0><<<dim3(12, 16), 256, 0, stream>>>(
            (const short*)ff1, (const short*)wff2T[i], ff_b2 + (size_t)i*EDIM, x, x, nullptr,
            NROW, EDIM, 4*EDIM);
    }

    // ---- final LN(x0 + x) + head ----
    ln_wave<EDIM><<<NROW/4, 256, 0, stream>>>(x, x0, fin_g, fin_b, h);
    gemm64t<0,0><<<dim3(16, 16), 256, 0, stream>>>(
        (const short*)h, (const short*)wheadT, head_b, nullptr, logits, nullptr,
        NROW, PDIM*VDIM, EDIM);

    // ---- sa block over (B*T*P, V) ----
    ln_wave<VDIM><<<NROW2/4, 256, 0, stream>>>(logits, nullptr, sa_ln0_g, sa_ln0_b, h2);
    gemm64q<3><<<dim3(36, 64), 256, 0, stream>>>(
        (const short*)h2, (const short*)wsaqkvT, nullptr, qkv2,
        nullptr, nullptr, nullptr, ropec, ropes, NROW2, 3*EDIM, VDIM);
    sa_attn<<<dim3(TSEQ, NHEAD, BB), 256, 0, stream>>>(qkv2, sa_o);
    gemm64t<1,0><<<dim3(4, 64), 256, 0, stream>>>(
        (const short*)sa_o, (const short*)wsaprojT, sa_proj_b, logits, logits, nullptr,
        NROW2, VDIM, EDIM);
    ln_wave<VDIM><<<NROW2/4, 256, 0, stream>>>(logits, nullptr, sa_ln1_g, sa_ln1_b, h2);
    gemm64q<1><<<dim3(16, 64), 256, 0, stream>>>(
        (const short*)h2, (const short*)wsaff1T, sa_ff_b1, sa_f1,
        nullptr, nullptr, nullptr, nullptr, nullptr, NROW2, 4*VDIM, VDIM);
    gemm64t<1,1><<<dim3(4, 64), 256, 0, stream>>>(
        (const short*)sa_f1, (const short*)wsaff2T, sa_ff_b2, logits, logits, out,
        NROW2, VDIM, 4*VDIM);
}

// Round 13
// 661.478 us; speedup vs baseline: 1.0696x; 1.0696x over previous
//
#include <hip/hip_runtime.h>
#include <hip/hip_bf16.h>
#include <cstdint>
#include <cstddef>

#define BB    2
#define TSEQ  512
#define EDIM  768
#define NHEAD 12
#define HDIM  64
#define VDIM  256
#define PDIM  4
#define NROW  (BB*TSEQ)        // 1024
#define NROW2 (BB*TSEQ*PDIM)   // 4096

typedef __attribute__((ext_vector_type(8))) short short8;
typedef __attribute__((ext_vector_type(4))) short short4v;
typedef __attribute__((ext_vector_type(4))) float floatx4;

__device__ __forceinline__ float gelu_f(float v){
    return 0.5f * v * (1.0f + erff(v * 0.70710678118654752f));
}
__device__ __forceinline__ float b2f(short s){
    unsigned u = ((unsigned)(unsigned short)s) << 16;
    float f; __builtin_memcpy(&f, &u, 4); return f;
}
__device__ __forceinline__ short f2bs(float v){
    __hip_bfloat16 h = __float2bfloat16(v);
    short s; __builtin_memcpy(&s, &h, 2); return s;
}
__device__ __forceinline__ void gload16(const void* g, void* l){
    __builtin_amdgcn_global_load_lds((const __attribute__((address_space(1))) void*)g,
                                     (__attribute__((address_space(3))) void*)l, 16, 0, 0);
}

// emit s_waitcnt vmcnt(<literal n>)
#define WAITN(n) asm volatile("s_waitcnt vmcnt(" #n ")" ::: "memory")
// 4-stage pipeline wait: steady keeps 2 future stages in flight.
#define WAIT_STAGE(rem, full, half)                         \
    do{ if((rem) >= 2)      WAITN(full);                    \
        else if((rem) == 1) WAITN(half);                    \
        else                WAITN(0);                       \
        asm volatile("s_barrier" ::: "memory"); }while(0)

// ---------------------------------------------------------------------------
// All 17 weight conversions in one dispatch. fp32 [K,N] -> bf16 [N,K].
// 128x128 tiles; 8-deep load batches; bf16 LDS with XOR swizzle.
// ---------------------------------------------------------------------------
struct WD2 { const float* in; __hip_bfloat16* out; int K; int N; int nt; };
struct WDs { WD2 d[17]; };

__global__ __launch_bounds__(256) void wconv_all(WDs a)
{
    int id = blockIdx.x;
    int i = 0;
    while(i < 16 && id >= a.d[i].nt){ id -= a.d[i].nt; i++; }
    WD2 w = a.d[i];
    const int tx = w.N / 128;
    const int n0 = (id % tx) * 128, k0 = (id / tx) * 128;
    __shared__ short t[128*128];           // 32 KB, bf16, swizzled
    {
        const int c4 = (threadIdx.x & 31) * 4;   // n within tile
        const int r0 = threadIdx.x >> 5;         // 0..7
        #pragma unroll
        for(int half = 0; half < 2; half++){
            float4 v[8];
            #pragma unroll
            for(int it = 0; it < 8; it++){
                int r = r0 + it*8 + half*64;
                v[it] = *(const float4*)(w.in + (size_t)(k0 + r) * w.N + n0 + c4);
            }
            #pragma unroll
            for(int it = 0; it < 8; it++){
                int r = r0 + it*8 + half*64;
                int nswz = c4 ^ (((r >> 3) & 15) << 2);
                short4v o;
                o[0] = f2bs(v[it].x); o[1] = f2bs(v[it].y);
                o[2] = f2bs(v[it].z); o[3] = f2bs(v[it].w);
                *(short4v*)&t[r*128 + nswz] = o;
            }
        }
    }
    __syncthreads();
    {
        const int k8 = (threadIdx.x & 15) * 8;     // 0..120
        const int nr = threadIdx.x >> 4;           // 0..15
        const int swz = (k8 >> 3) << 2;
        #pragma unroll
        for(int pass = 0; pass < 8; pass++){
            int n = nr + pass*16;
            int nswz = n ^ swz;
            short8 o;
            #pragma unroll
            for(int j = 0; j < 8; j++) o[j] = t[(k8 + j)*128 + nswz];
            *(short8*)((short*)w.out + (size_t)(n0 + n) * w.K + k0 + k8) = o;
        }
    }
}

// ---------------------------------------------------------------------------
// MFMA GEMM 64x64 "q" variant: 4 waves, each owning 16 rows x ALL 64 cols
// (acc[4] along N). 32 KB LDS -> 5 blocks/CU; 4-stage counted-vmcnt.
// EPI: 1 = bias+gelu bf16; 2 = layer-qkv RoPE head-major; 3 = SA RoPE (p=row%4).
// ---------------------------------------------------------------------------
template<int EPI>
__global__ __launch_bounds__(256) void gemm64q(
    const short* __restrict__ A, const short* __restrict__ Bt,
    const float* __restrict__ bias, __hip_bfloat16* __restrict__ Cout,
    __hip_bfloat16* __restrict__ qrb, __hip_bfloat16* __restrict__ krb,
    __hip_bfloat16* __restrict__ vvb,
    const float* __restrict__ rc, const float* __restrict__ rs,
    int M, int N, int K)
{
    alignas(16) __shared__ short As[4*64*32];    // 16 KB
    alignas(16) __shared__ short Bs[4*64*32];    // 16 KB
    const int tid  = threadIdx.x;
    const int lane = tid & 63;
    const int wave = tid >> 6;
    const int bm = blockIdx.y * 64, bn = blockIdx.x * 64;
    const int wm = wave * 16;                    // 16 rows per wave
    const int quad = lane >> 4, l16 = lane & 15;

    floatx4 acc[4];
    #pragma unroll
    for(int j = 0; j < 4; j++) acc[j] = floatx4{0.f, 0.f, 0.f, 0.f};

    const int r  = tid >> 2;
    const int c8 = (tid & 3) * 8;
    const int ldsoff = (tid & 192) * 16;

    auto issue = [&](int k0, int cur){
        char* ab = (char*)As + cur*4096 + ldsoff;
        char* bb = (char*)Bs + cur*4096 + ldsoff;
        gload16(A  + (size_t)(bm + r) * K + k0 + c8, ab);
        gload16(Bt + (size_t)(bn + r) * K + k0 + c8, bb);
    };

    const int niter = K >> 5;                 // >= 8 at all call sites
    issue(0, 0); issue(32, 1); issue(64, 2);
    for(int it = 0; it < niter; it++){
        WAIT_STAGE(niter - 1 - it, 4, 2);     // 2 loads/issue
        if(it + 3 < niter) issue((it + 3) << 5, (it + 3) & 3);
        const short* Ab = As + (it & 3) * 2048;
        const short* Bb = Bs + (it & 3) * 2048;
        short8 af = *(const short8*)&Ab[(wm + l16)*32 + quad*8];
        short8 bfr[4];
        #pragma unroll
        for(int j = 0; j < 4; j++)
            bfr[j] = *(const short8*)&Bb[(j*16 + l16)*32 + quad*8];
        #pragma unroll
        for(int j = 0; j < 4; j++)
            acc[j] = __builtin_amdgcn_mfma_f32_16x16x32_bf16(af, bfr[j], acc[j], 0, 0, 0);
    }

    if(EPI == 2){
        // layer qkv: RoPE + head-major stores. Wave holds all 64 cols (one head).
        const int region = bn / 768;       // 0=q, 1=k, 2=v
        const int h = (bn % 768) >> 6;
        #pragma unroll
        for(int rr = 0; rr < 4; rr++){
            int row = bm + wm + quad*4 + rr;
            int t = row & (TSEQ-1), b = row >> 9;
            float a0 = acc[0][rr], a1 = acc[1][rr];
            float a2 = acc[2][rr], a3 = acc[3][rr];
            size_t dbase = ((size_t)(b*NHEAD + h)*TSEQ + t)*HDIM;
            if(region == 2){
                vvb[dbase + l16]      = __float2bfloat16(a0);
                vvb[dbase + 16 + l16] = __float2bfloat16(a1);
                vvb[dbase + 32 + l16] = __float2bfloat16(a2);
                vvb[dbase + 48 + l16] = __float2bfloat16(a3);
            }else{
                float c0 = rc[t*32 + l16],      s0 = rs[t*32 + l16];
                float c1 = rc[t*32 + 16 + l16], s1 = rs[t*32 + 16 + l16];
                __hip_bfloat16* dst = (region == 0) ? qrb : krb;
                dst[dbase + l16]      = __float2bfloat16(a0*c0 - a2*s0);
                dst[dbase + 16 + l16] = __float2bfloat16(a1*c1 - a3*s1);
                dst[dbase + 32 + l16] = __float2bfloat16(a0*s0 + a2*c0);
                dst[dbase + 48 + l16] = __float2bfloat16(a1*s1 + a3*c1);
            }
        }
        return;
    }

    if(EPI == 3){
        // SA qkv: RoPE at p = row%4, row-major bf16 store.
        const int region = bn / 768;
        #pragma unroll
        for(int rr = 0; rr < 4; rr++){
            int row = bm + wm + quad*4 + rr;
            float a0 = acc[0][rr], a1 = acc[1][rr];
            float a2 = acc[2][rr], a3 = acc[3][rr];
            size_t rowb = (size_t)row * N + bn;
            if(region == 2){
                Cout[rowb + l16]      = __float2bfloat16(a0);
                Cout[rowb + 16 + l16] = __float2bfloat16(a1);
                Cout[rowb + 32 + l16] = __float2bfloat16(a2);
                Cout[rowb + 48 + l16] = __float2bfloat16(a3);
            }else{
                int p = row & 3;
                float c0 = rc[p*32 + l16],      s0 = rs[p*32 + l16];
                float c1 = rc[p*32 + 16 + l16], s1 = rs[p*32 + 16 + l16];
                Cout[rowb + l16]      = __float2bfloat16(a0*c0 - a2*s0);
                Cout[rowb + 16 + l16] = __float2bfloat16(a1*c1 - a3*s1);
                Cout[rowb + 32 + l16] = __float2bfloat16(a0*s0 + a2*c0);
                Cout[rowb + 48 + l16] = __float2bfloat16(a1*s1 + a3*c1);
            }
        }
        return;
    }

    // EPI == 1: bias + gelu, bf16 store
    #pragma unroll
    for(int j = 0; j < 4; j++){
        int col = bn + j*16 + l16;
        float bv = bias ? bias[col] : 0.f;
        #pragma unroll
        for(int rr = 0; rr < 4; rr++){
            int row = bm + wm + quad*4 + rr;
            float v = acc[j][rr] + bv;
            v = gelu_f(v);
            Cout[(size_t)row * N + col] = __float2bfloat16(v);
        }
    }
}

// ---------------------------------------------------------------------------
// 64x64-tile GEMM (bf16 A), 4-stage counted-vmcnt; fp32 out, optional resid
// add and fused p==0 slice copy to out (OUTC).  (r10 proven form)
// ---------------------------------------------------------------------------
template<int RESID, int OUTC>
__global__ __launch_bounds__(256) void gemm64t(
    const short* __restrict__ A, const short* __restrict__ Bt,
    const float* __restrict__ bias, const float* __restrict__ resid,
    float* __restrict__ Cf, float* __restrict__ outp, int M, int N, int K)
{
    alignas(16) __shared__ short As[4*64*32];    // 16 KB
    alignas(16) __shared__ short Bs[4*64*32];    // 16 KB
    const int tid  = threadIdx.x;
    const int lane = tid & 63;
    const int wave = tid >> 6;
    const int bm = blockIdx.y * 64, bn = blockIdx.x * 64;
    const int wm = (wave >> 1) * 32, wn = (wave & 1) * 32;
    const int quad = lane >> 4, l16 = lane & 15;

    floatx4 acc[2][2];
    #pragma unroll
    for(int i = 0; i < 2; i++)
        #pragma unroll
        for(int j = 0; j < 2; j++)
            acc[i][j] = floatx4{0.f, 0.f, 0.f, 0.f};

    const int r  = tid >> 2;
    const int c8 = (tid & 3) * 8;
    const int ldsoff = (tid & 192) * 16;

    auto issue = [&](int k0, int cur){
        char* ab = (char*)As + cur*4096 + ldsoff;
        char* bb = (char*)Bs + cur*4096 + ldsoff;
        gload16(A  + (size_t)(bm + r) * K + k0 + c8, ab);
        gload16(Bt + (size_t)(bn + r) * K + k0 + c8, bb);
    };

    const int niter = K >> 5;
    issue(0, 0); issue(32, 1); issue(64, 2);
    for(int it = 0; it < niter; it++){
        WAIT_STAGE(niter - 1 - it, 4, 2);     // 2 loads/issue
        if(it + 3 < niter) issue((it + 3) << 5, (it + 3) & 3);
        const short* Ab = As + (it & 3) * 2048;
        const short* Bb = Bs + (it & 3) * 2048;
        short8 af[2], bfr[2];
        #pragma unroll
        for(int i = 0; i < 2; i++){
            af[i]  = *(const short8*)&Ab[(wm + i*16 + l16)*32 + quad*8];
            bfr[i] = *(const short8*)&Bb[(wn + i*16 + l16)*32 + quad*8];
        }
        #pragma unroll
        for(int i = 0; i < 2; i++)
            #pragma unroll
            for(int j = 0; j < 2; j++)
                acc[i][j] = __builtin_amdgcn_mfma_f32_16x16x32_bf16(af[i], bfr[j], acc[i][j], 0, 0, 0);
    }

    #pragma unroll
    for(int i = 0; i < 2; i++){
        int row0 = bm + wm + i*16 + quad*4;
        #pragma unroll
        for(int j = 0; j < 2; j++){
            int col = bn + wn + j*16 + l16;
            float bv = bias ? bias[col] : 0.f;
            #pragma unroll
            for(int rr = 0; rr < 4; rr++){
                int row = row0 + rr;
                float v = acc[i][j][rr] + bv;
                if(RESID) v += resid[(size_t)row * N + col];
                Cf[(size_t)row * N + col] = v;
                if(OUTC && (row & 3) == 0)
                    outp[(size_t)(row >> 2) * N + col] = v;
            }
        }
    }
}

// ---------------------------------------------------------------------------
// LayerNorm, wave-per-row (4 rows/block). fp32 in (optionally +in2), bf16 out.
// ---------------------------------------------------------------------------
template<int D>
__global__ __launch_bounds__(256) void ln_wave(
    const float* __restrict__ in, const float* __restrict__ in2,
    const float* __restrict__ g, const float* __restrict__ bta,
    __hip_bfloat16* __restrict__ out)
{
    constexpr int NC = D / 256;                 // float4 chunks per lane
    const int row  = blockIdx.x * 4 + (threadIdx.x >> 6);
    const int lane = threadIdx.x & 63;
    const float* xr = in + (size_t)row * D;
    float4 v[NC];
    float sum = 0.f, sq = 0.f;
    #pragma unroll
    for(int j = 0; j < NC; j++){
        int d0 = (lane + 64*j) * 4;
        v[j] = *(const float4*)(xr + d0);
        if(in2){
            float4 u = *(const float4*)(in2 + (size_t)row * D + d0);
            v[j].x += u.x; v[j].y += u.y; v[j].z += u.z; v[j].w += u.w;
        }
        sum += v[j].x + v[j].y + v[j].z + v[j].w;
        sq  += v[j].x*v[j].x + v[j].y*v[j].y + v[j].z*v[j].z + v[j].w*v[j].w;
    }
    #pragma unroll
    for(int off = 32; off > 0; off >>= 1){
        sum += __shfl_xor(sum, off, 64);
        sq  += __shfl_xor(sq,  off, 64);
    }
    const float m    = sum / D;
    const float rstd = rsqrtf(fmaxf(sq / D - m*m, 0.f) + 1e-5f);
    #pragma unroll
    for(int j = 0; j < NC; j++){
        int d0 = (lane + 64*j) * 4;
        float4 gg = *(const float4*)(g + d0);
        float4 bb = *(const float4*)(bta + d0);
        short4v o;
        o[0] = f2bs((v[j].x - m) * rstd * gg.x + bb.x);
        o[1] = f2bs((v[j].y - m) * rstd * gg.y + bb.y);
        o[2] = f2bs((v[j].z - m) * rstd * gg.z + bb.z);
        o[3] = f2bs((v[j].w - m) * rstd * gg.w + bb.w);
        *(short4v*)((short*)out + (size_t)row * D + d0) = o;
    }
}

// ---------------------------------------------------------------------------
// Fused embed (blocks 0..NROW-1) + rope table build (blocks NROW..NROW+63).
// ---------------------------------------------------------------------------
__global__ __launch_bounds__(256) void embed_rope(
    const int* __restrict__ tokens, const float* __restrict__ emb,
    float* __restrict__ x0, float* __restrict__ x,
    float* __restrict__ rc, float* __restrict__ rs)
{
    const int blk = blockIdx.x;
    if(blk < NROW){
        const int tok = tokens[blk];
        const float4* src = (const float4*)(emb + (size_t)tok * EDIM);
        float4* d0 = (float4*)(x0 + (size_t)blk * EDIM);
        float4* d1 = (float4*)(x  + (size_t)blk * EDIM);
        if(threadIdx.x < EDIM/4){
            float4 v = src[threadIdx.x]; d0[threadIdx.x] = v; d1[threadIdx.x] = v;
        }
        return;
    }
    int i = (blk - NROW) * 256 + threadIdx.x;   // 64*256 = 16384
    int pos = i >> 5, d = i & 31;
    float inv = powf(10000.0f, -(float)(2*d) / 64.0f);
    float f = (float)pos * inv;
    rc[i] = cosf(f);
    rs[i] = sinf(f);
}

// ---------------------------------------------------------------------------
// Sliding-window attention. 16 queries/block (4 waves x 4 queries each),
// shared S+15-row K/V window. PV runs an absolute-row loop shared across the
// wave's 4 queries (one V read per row, zero-padded p rows) — 1.6x fewer LDS
// ops, 4x fewer V-address calcs; identical arithmetic order (pads add +0.0).
// ---------------------------------------------------------------------------
template<int S>
__global__ __launch_bounds__(256) void patch_attn16(
    const __hip_bfloat16* __restrict__ qr, const __hip_bfloat16* __restrict__ kr,
    const __hip_bfloat16* __restrict__ vv, float* __restrict__ x)
{
    constexpr int W = S + 15;
    constexpr int PBW = S + 8;                 // 4 zero slots each side
    alignas(16) __shared__ short Ks[W*64];
    alignas(16) __shared__ short Vs[W*64];
    __shared__ float qlds[16*64];
    __shared__ float pb[16*PBW];

    const int t0 = blockIdx.x * 16;
    const int h = blockIdx.y, b = blockIdx.z;
    const int tid = threadIdx.x;
    const int wv = tid >> 6, lane = tid & 63;
    const size_t headbase = ((size_t)(b*NHEAD + h)) * TSEQ;

    const int c = tid & 7;
    for(int r = tid >> 3; r < W; r += 32){
        int g = t0 - S + 1 + r;
        int gc = g < 0 ? 0 : g;
        int sc = (c ^ (r & 7)) * 8;
        *(short8*)&Ks[r*64 + sc] = *(const short8*)((const short*)kr + (headbase + gc)*64 + c*8);
        *(short8*)&Vs[r*64 + sc] = *(const short8*)((const short*)vv + (headbase + gc)*64 + c*8);
    }
    for(int i = tid; i < 16*64; i += 256)
        qlds[i] = __bfloat162float(qr[(headbase + t0 + (i >> 6))*64 + (i & 63)]);
    __syncthreads();

    #pragma unroll
    for(int qq = 0; qq < 4; qq++){
        const int ql = wv*4 + qq;          // local query index 0..15
        const int t  = t0 + ql;
        const int r0 = (S >= 64) ? (ql + lane) : ((lane < S) ? (ql + lane) : 0);
        const int r1 = ql + lane + 64;
        float a0 = 0.f, a1 = 0.f;
        #pragma unroll
        for(int ch = 0; ch < 8; ch++){
            float4 qa = *(const float4*)&qlds[ql*64 + ch*8];
            float4 qb = *(const float4*)&qlds[ql*64 + ch*8 + 4];
            short8 k0 = *(const short8*)&Ks[r0*64 + ((ch ^ (r0 & 7))*8)];
            a0 += qa.x*b2f(k0[0]) + qa.y*b2f(k0[1]) + qa.z*b2f(k0[2]) + qa.w*b2f(k0[3])
                + qb.x*b2f(k0[4]) + qb.y*b2f(k0[5]) + qb.z*b2f(k0[6]) + qb.w*b2f(k0[7]);
            if(S == 128){
                short8 k1 = *(const short8*)&Ks[r1*64 + ((ch ^ (r1 & 7))*8)];
                a1 += qa.x*b2f(k1[0]) + qa.y*b2f(k1[1]) + qa.z*b2f(k1[2]) + qa.w*b2f(k1[3])
                    + qb.x*b2f(k1[4]) + qb.y*b2f(k1[5]) + qb.z*b2f(k1[6]) + qb.w*b2f(k1[7]);
            }
        }
        const int key0 = t - S + 1 + lane;
        const bool v0 = (lane < S) && (key0 >= 0);
        const bool v1 = (S == 128) && (key0 + 64 >= 0);
        float s0 = v0 ? a0 * 0.125f : -1e30f;
        float s1 = v1 ? a1 * 0.125f : -1e30f;
        float mx = fmaxf(s0, s1);
        #pragma unroll
        for(int off = 32; off > 0; off >>= 1) mx = fmaxf(mx, __shfl_xor(mx, off, 64));
        float p0 = v0 ? expf(s0 - mx) : 0.f;
        float p1 = v1 ? expf(s1 - mx) : 0.f;
        float sm = p0 + p1;
        #pragma unroll
        for(int off = 32; off > 0; off >>= 1) sm += __shfl_xor(sm, off, 64);
        const float inv = 1.f / sm;
        if(lane < S) pb[ql*PBW + 4 + lane] = p0 * inv;
        if(S == 128) pb[ql*PBW + 4 + 64 + lane] = p1 * inv;
        if(lane < 4){
            pb[ql*PBW + lane] = 0.f;           // leading pad
            pb[ql*PBW + 4 + S + lane] = 0.f;   // trailing pad
        }
    }
    // pb rows are wave-local (each wave reads only its own ql rows) -> no barrier

    const int d = lane;
    const int coff = d >> 3, dlo = d & 7;
    const int rb = wv*4;
    const int p0b = (rb+0)*PBW + 4;
    const int p1b = (rb+1)*PBW + 3;
    const int p2b = (rb+2)*PBW + 2;
    const int p3b = (rb+3)*PBW + 1;
    float o0 = 0.f, o1 = 0.f, o2 = 0.f, o3 = 0.f;
    #pragma unroll 8
    for(int rr = 0; rr <= S + 2; rr++){
        int r = rb + rr;
        float v = b2f(Vs[r*64 + ((coff ^ (r & 7))*8) + dlo]);
        o0 += pb[p0b + rr] * v;
        o1 += pb[p1b + rr] * v;
        o2 += pb[p2b + rr] * v;
        o3 += pb[p3b + rr] * v;
    }
    float* xp = x + ((size_t)(b*TSEQ) + t0 + rb) * EDIM + h*HDIM + d;
    xp[0*EDIM] += o0;
    xp[1*EDIM] += o1;
    xp[2*EDIM] += o2;
    xp[3*EDIM] += o3;
}

// ---------------------------------------------------------------------------
// P-axis attention: q/k already rotated by saqkv epilogue.
// ---------------------------------------------------------------------------
__global__ __launch_bounds__(256) void sa_attn(
    const __hip_bfloat16* __restrict__ qkv2, __hip_bfloat16* __restrict__ o)
{
    const int t = blockIdx.x, h = blockIdx.y, b = blockIdx.z;
    const int p = threadIdx.x >> 6, lane = threadIdx.x & 63;
    const int row0 = (b*TSEQ + t) * PDIM;
    const short* base = (const short*)qkv2 + (size_t)row0 * (3*EDIM);
    const int d = lane;
    float q = b2f(base[(size_t)p*(3*EDIM) + h*HDIM + d]);
    float sc[4];
    #pragma unroll
    for(int j = 0; j < 4; j++){
        float kj = b2f(base[(size_t)j*(3*EDIM) + EDIM + h*HDIM + d]);
        float v = q * kj;
        #pragma unroll
        for(int off = 32; off > 0; off >>= 1) v += __shfl_xor(v, off, 64);
        sc[j] = v * 0.125f;
    }
    float m = fmaxf(fmaxf(sc[0], sc[1]), fmaxf(sc[2], sc[3]));
    float e0 = expf(sc[0]-m), e1 = expf(sc[1]-m), e2 = expf(sc[2]-m), e3 = expf(sc[3]-m);
    float idn = 1.f / (e0 + e1 + e2 + e3);
    float ov = (e0 * b2f(base[0*(3*EDIM) + 2*EDIM + h*HDIM + d])
              + e1 * b2f(base[1*(3*EDIM) + 2*EDIM + h*HDIM + d])
              + e2 * b2f(base[2*(3*EDIM) + 2*EDIM + h*HDIM + d])
              + e3 * b2f(base[3*(3*EDIM) + 2*EDIM + h*HDIM + d])) * idn;
    o[(size_t)(row0 + p) * EDIM + h*HDIM + d] = __float2bfloat16(ov);
}

// ---------------------------------------------------------------------------
extern "C" void kernel_launch(void* const* d_in, const int* in_sizes, int n_in,
                              void* d_out, int out_size, void* d_ws, size_t ws_size,
                              hipStream_t stream)
{
    const int*   tokens    = (const int*)  d_in[0];
    const float* emb       = (const float*)d_in[1];
    const float* bl0g      = (const float*)d_in[2];
    const float* bl0b      = (const float*)d_in[3];
    const float* bl1g      = (const float*)d_in[4];
    const float* bl1b      = (const float*)d_in[5];
    const float* qkv_w     = (const float*)d_in[6];
    const float* ff_w1     = (const float*)d_in[7];
    const float* ff_b1     = (const float*)d_in[8];
    const float* ff_w2     = (const float*)d_in[9];
    const float* ff_b2     = (const float*)d_in[10];
    const float* fin_g     = (const float*)d_in[11];
    const float* fin_b     = (const float*)d_in[12];
    const float* head_w    = (const float*)d_in[13];
    const float* head_b    = (const float*)d_in[14];
    const float* sa_ln0_g  = (const float*)d_in[15];
    const float* sa_ln0_b  = (const float*)d_in[16];
    const float* sa_ln1_g  = (const float*)d_in[17];
    const float* sa_ln1_b  = (const float*)d_in[18];
    const float* sa_qkv_w  = (const float*)d_in[19];
    const float* sa_proj_w = (const float*)d_in[20];
    const float* sa_proj_b = (const float*)d_in[21];
    const float* sa_ff_w1  = (const float*)d_in[22];
    const float* sa_ff_b1  = (const float*)d_in[23];
    const float* sa_ff_w2  = (const float*)d_in[24];
    const float* sa_ff_b2  = (const float*)d_in[25];
    float* out = (float*)d_out;

    // ---- workspace carve-up (~94 MB; harness provides 256 MiB) ----
    char* p = (char*)d_ws;
    auto alloc = [&](size_t bytes){ char* q = p; p += (bytes + 255) & ~(size_t)255; return q; };

    float* logits = (float*)alloc((size_t)NROW2*VDIM*4);        // 4 MB
    float* ropec  = (float*)alloc(512*32*4);
    float* ropes  = (float*)alloc(512*32*4);
    __hip_bfloat16* wqkvT[4]; for(int i=0;i<4;i++) wqkvT[i] = (__hip_bfloat16*)alloc((size_t)768*2304*2);
    __hip_bfloat16* wff1T[4]; for(int i=0;i<4;i++) wff1T[i] = (__hip_bfloat16*)alloc((size_t)768*3072*2);
    __hip_bfloat16* wff2T[4]; for(int i=0;i<4;i++) wff2T[i] = (__hip_bfloat16*)alloc((size_t)3072*768*2);
    __hip_bfloat16* wheadT   = (__hip_bfloat16*)alloc((size_t)768*1024*2);
    __hip_bfloat16* wsaqkvT  = (__hip_bfloat16*)alloc((size_t)256*2304*2);
    __hip_bfloat16* wsaprojT = (__hip_bfloat16*)alloc((size_t)768*256*2);
    __hip_bfloat16* wsaff1T  = (__hip_bfloat16*)alloc((size_t)256*1024*2);
    __hip_bfloat16* wsaff2T  = (__hip_bfloat16*)alloc((size_t)1024*256*2);
    char* U = p;
    // phase 1
    float* x0           = (float*)(U);                           // 3,145,728
    float* x            = (float*)(U + 3145728);                 // 3,145,728
    __hip_bfloat16* h   = (__hip_bfloat16*)(U + 6291456);        // 1,572,864
    __hip_bfloat16* ff1 = (__hip_bfloat16*)(U + 7864320);        // 6,291,456
    __hip_bfloat16* qrb = (__hip_bfloat16*)(U + 14155776);       // 1,572,864
    __hip_bfloat16* krb = (__hip_bfloat16*)(U + 15728640);       // 1,572,864
    __hip_bfloat16* vvb = (__hip_bfloat16*)(U + 17301504);       // 1,572,864
    // phase 2 (aliases phase 1 — dead after head GEMM)
    __hip_bfloat16* h2    = (__hip_bfloat16*)(U);                // 2,097,152
    __hip_bfloat16* qkv2  = (__hip_bfloat16*)(U + 2097152);      // 18,874,368
    __hip_bfloat16* sa_o  = (__hip_bfloat16*)(U + 20971520);     // 6,291,456
    __hip_bfloat16* sa_f1 = (__hip_bfloat16*)(U + 27262976);     // 8,388,608

    // ---- prologue: embed+rope fused + all 17 weight converts in ONE dispatch ----
    embed_rope<<<NROW + 64, 256, 0, stream>>>(tokens, emb, x0, x, ropec, ropes);
    {
        WDs wds; int tot = 0, n = 0;
        auto add = [&](const float* in, __hip_bfloat16* o2, int K, int N){
            wds.d[n++] = WD2{in, o2, K, N, (N/128)*(K/128)};
            tot += (N/128)*(K/128);
        };
        for(int i=0;i<4;i++){
            add(qkv_w + (size_t)i*768*2304, wqkvT[i], 768, 2304);
            add(ff_w1 + (size_t)i*768*3072, wff1T[i], 768, 3072);
            add(ff_w2 + (size_t)i*3072*768, wff2T[i], 3072, 768);
        }
        add(head_w,    wheadT,   768, 1024);
        add(sa_qkv_w,  wsaqkvT,  256, 2304);
        add(sa_proj_w, wsaprojT, 768, 256);
        add(sa_ff_w1,  wsaff1T,  256, 1024);
        add(sa_ff_w2,  wsaff2T, 1024, 256);
        wconv_all<<<tot, 256, 0, stream>>>(wds);
    }

    // ---- 4 main layers ----
    for(int i = 0; i < 4; i++){
        ln_wave<EDIM><<<NROW/4, 256, 0, stream>>>(x, nullptr, bl0g + i*EDIM, bl0b + i*EDIM, h);
        gemm64q<2><<<dim3(36, 16), 256, 0, stream>>>(
            (const short*)h, (const short*)wqkvT[i], nullptr, nullptr,
            qrb, krb, vvb, ropec, ropes, NROW, 3*EDIM, EDIM);
        dim3 agrid(TSEQ/16, NHEAD, BB);
        if(i == 0)      patch_attn16<16><<<agrid, 256, 0, stream>>>(qrb, krb, vvb, x);
        else if(i == 1) patch_attn16<32><<<agrid, 256, 0, stream>>>(qrb, krb, vvb, x);
        else if(i == 2) patch_attn16<64><<<agrid, 256, 0, stream>>>(qrb, krb, vvb, x);
        else            patch_attn16<128><<<agrid, 256, 0, stream>>>(qrb, krb, vvb, x);
        ln_wave<EDIM><<<NROW/4, 256, 0, stream>>>(x, nullptr, bl1g + i*EDIM, bl1b + i*EDIM, h);
        gemm64q<1><<<dim3(48, 16), 256, 0, stream>>>(
            (const short*)h, (const short*)wff1T[i], ff_b1 + (size_t)i*4*EDIM, ff1,
            nullptr, nullptr, nullptr, nullptr, nullptr, NROW, 4*EDIM, EDIM);
        gemm64t<1,0><<<dim3(12, 16), 256, 0, stream>>>(
            (const short*)ff1, (const short*)wff2T[i], ff_b2 + (size_t)i*EDIM, x, x, nullptr,
            NROW, EDIM, 4*EDIM);
    }

    // ---- final LN(x0 + x) + head ----
    ln_wave<EDIM><<<NROW/4, 256, 0, stream>>>(x, x0, fin_g, fin_b, h);
    gemm64t<0,0><<<dim3(16, 16), 256, 0, stream>>>(
        (const short*)h, (const short*)wheadT, head_b, nullptr, logits, nullptr,
        NROW, PDIM*VDIM, EDIM);

    // ---- sa block over (B*T*P, V) ----
    ln_wave<VDIM><<<NROW2/4, 256, 0, stream>>>(logits, nullptr, sa_ln0_g, sa_ln0_b, h2);
    gemm64q<3><<<dim3(36, 64), 256, 0, stream>>>(
        (const short*)h2, (const short*)wsaqkvT, nullptr, qkv2,
        nullptr, nullptr, nullptr, ropec, ropes, NROW2, 3*EDIM, VDIM);
    sa_attn<<<dim3(TSEQ, NHEAD, BB), 256, 0, stream>>>(qkv2, sa_o);
    gemm64t<1,0><<<dim3(4, 64), 256, 0, stream>>>(
        (const short*)sa_o, (const short*)wsaprojT, sa_proj_b, logits, logits, nullptr,
        NROW2, VDIM, EDIM);
    ln_wave<VDIM><<<NROW2/4, 256, 0, stream>>>(logits, nullptr, sa_ln1_g, sa_ln1_b, h2);
    gemm64q<1><<<dim3(16, 64), 256, 0, stream>>>(
        (const short*)h2, (const short*)wsaff1T, sa_ff_b1, sa_f1,
        nullptr, nullptr, nullptr, nullptr, nullptr, NROW2, 4*VDIM, VDIM);
    gemm64t<1,1><<<dim3(4, 64), 256, 0, stream>>>(
        (const short*)sa_f1, (const short*)wsaff2T, sa_ff_b2, logits, logits, out,
        NROW2, VDIM, 4*VDIM);
}